// Round 7
// baseline (372.023 us; speedup 1.0000x reference)
//
#include <hip/hip_runtime.h>
#include <math.h>

// Problem constants
#define NTHETA  360
#define NLAMBDA 720
#define MMAX    361
#define NROWS   2880                       /* 8 heads * 360 theta rows */
#define ANGD (6.283185307179586476925286766559 / 720.0)  /* 2*pi/720 */

// DFT tiling
#define MT 128          /* m-tile per block (3 tiles cover 384 >= 361)   */
#define RT 64           /* row-tile per block (45 tiles cover 2880)      */
#define JC 36           /* j chunk staged in LDS (divides 720/S, mult 4) */
#define MPAD 384        /* padded m extent of cos table / partials       */

// Workspace: Tc[720][384] floats, then P[S][384][2880] floats
#define TC_ELEMS   ((size_t)720 * MPAD)            /* 276,480 floats  */
#define P_STRIDE   ((size_t)MPAD * NROWS)          /* 1,105,920 floats */

// ---------------------------------------------------------------------------
// Cos table: Tc[j*384+mp] = (2pi/720)*cos(2pi*(j*mp mod 720)/720), 0 for mp>=361.
// ---------------------------------------------------------------------------
__global__ __launch_bounds__(256) void tw_init_kernel(float* __restrict__ Tc) {
    int i = blockIdx.x * 256 + threadIdx.x;
    if (i >= (int)TC_ELEMS) return;
    int j = i / MPAD, mp = i % MPAD;
    float v = 0.f;
    if (mp < MMAX) {
        int p = (j * mp) % 720;                      // exact integer phase
        v = (float)ANGD * cosf((float)(ANGD * (double)p));
    }
    Tc[i] = v;
}

// ---------------------------------------------------------------------------
// Real DFT as register-tiled GEMM:
//   P[s][mp][row] = sum_{j in split s} x[row][j] * Tc[j][mp]
// grid (3 mtile, 45 rtile, S), block 256 = (tm 16)x(tr 16); thread: 8m x 4r accs.
// ---------------------------------------------------------------------------
__global__ __launch_bounds__(256) void dft_re_kernel(
    const float* __restrict__ x, const float* __restrict__ Tc,
    float* __restrict__ P, int S) {
    const int mt  = blockIdx.x;
    const int rt  = blockIdx.y;
    const int s   = blockIdx.z;
    const int tid = threadIdx.x;
    const int tm  = tid & 15;
    const int tr  = tid >> 4;
    const int m0g = mt * MT;            // block m base (global)
    const int mo  = tm * 8;             // thread m offset in tile
    const int r0  = rt * RT + tr * 4;   // thread row base (always < 2880)
    const int jlen = 720 / S;
    const int j0   = s * jlen;

    __shared__ __align__(16) float tc[JC][MT + 4];

    float acc[8][4];
#pragma unroll
    for (int a = 0; a < 8; ++a)
#pragma unroll
        for (int b = 0; b < 4; ++b) acc[a][b] = 0.f;

    for (int jc = 0; jc < jlen; jc += JC) {
        __syncthreads();
        for (int i = tid; i < JC * MT; i += 256) {
            int jj = i >> 7;            // /128
            int mm = i & (MT - 1);
            tc[jj][mm] = Tc[(size_t)(j0 + jc + jj) * MPAD + m0g + mm];
        }
        __syncthreads();

        for (int j4 = 0; j4 < JC; j4 += 4) {
            float4 xv[4];
#pragma unroll
            for (int i = 0; i < 4; ++i)
                xv[i] = *(const float4*)&x[(size_t)(r0 + i) * 720 + (j0 + jc + j4)];
#pragma unroll
            for (int u = 0; u < 4; ++u) {
                float4 ta = *(const float4*)&tc[j4 + u][mo];
                float4 tb = *(const float4*)&tc[j4 + u][mo + 4];
#pragma unroll
                for (int i = 0; i < 4; ++i) {
                    float xe = (u == 0) ? xv[i].x : (u == 1) ? xv[i].y
                             : (u == 2) ? xv[i].z : xv[i].w;
                    acc[0][i] += ta.x * xe;
                    acc[1][i] += ta.y * xe;
                    acc[2][i] += ta.z * xe;
                    acc[3][i] += ta.w * xe;
                    acc[4][i] += tb.x * xe;
                    acc[5][i] += tb.y * xe;
                    acc[6][i] += tb.z * xe;
                    acc[7][i] += tb.w * xe;
                }
            }
        }
    }

#pragma unroll
    for (int mi = 0; mi < 8; ++mi) {
        float* dst = P + ((size_t)s * MPAD + m0g + mo + mi) * NROWS + r0;
        *(float4*)dst = make_float4(acc[mi][0], acc[mi][1], acc[mi][2], acc[mi][3]);
    }
}

// ---------------------------------------------------------------------------
// Contraction (real part only), S-partials summed during staging:
//   out[(h*360+n)*361+m] = sum_k (sum_s P[s][m][h*360+k]) * W[m][n][k]
// grid (3 nch, 361 m), block 256: n = nch*128 + tid/2, cg = tid&1 -> 4 heads.
// k unrolled x24: 6 independent float4 W loads in flight per thread.
// ---------------------------------------------------------------------------
__global__ __launch_bounds__(256) void contract_re_kernel(
    const float* __restrict__ W, const float* __restrict__ P,
    float* __restrict__ out, int S, long long out_elems) {
    const int nch = blockIdx.x;
    const int m   = blockIdx.y;
    const int tid = threadIdx.x;

    __shared__ __align__(16) float xl[NROWS];         // 11.5 KB
    for (int i = tid * 4; i < NROWS; i += 256 * 4) {
        float4 a = *(const float4*)&P[(size_t)m * NROWS + i];
        for (int s = 1; s < S; ++s) {
            float4 b = *(const float4*)&P[((size_t)s * MPAD + m) * NROWS + i];
            a.x += b.x; a.y += b.y; a.z += b.z; a.w += b.w;
        }
        *(float4*)&xl[i] = a;
    }
    __syncthreads();

    const int n  = nch * 128 + (tid >> 1);
    const int cg = tid & 1;
    if (n >= NTHETA) return;

    float a0 = 0.f, a1 = 0.f, a2 = 0.f, a3 = 0.f;
    const float* wr = W + ((size_t)m * 360 + n) * 360;
    const float* xb = xl + cg * 4 * 360;
    for (int k = 0; k < 360; k += 24) {
        float4 w[6];
#pragma unroll
        for (int q = 0; q < 6; ++q)
            w[q] = *(const float4*)(wr + k + q * 4);
#pragma unroll
        for (int q = 0; q < 6; ++q) {
            const int kk = k + q * 4;
            float4 v0 = *(const float4*)(xb + 0 * 360 + kk);
            float4 v1 = *(const float4*)(xb + 1 * 360 + kk);
            float4 v2 = *(const float4*)(xb + 2 * 360 + kk);
            float4 v3 = *(const float4*)(xb + 3 * 360 + kk);
            a0 += w[q].x * v0.x + w[q].y * v0.y + w[q].z * v0.z + w[q].w * v0.w;
            a1 += w[q].x * v1.x + w[q].y * v1.y + w[q].z * v1.z + w[q].w * v1.w;
            a2 += w[q].x * v2.x + w[q].y * v2.y + w[q].z * v2.z + w[q].w * v2.w;
            a3 += w[q].x * v3.x + w[q].y * v3.y + w[q].z * v3.z + w[q].w * v3.w;
        }
    }
    float av[4] = {a0, a1, a2, a3};
#pragma unroll
    for (int i = 0; i < 4; ++i) {
        int h = cg * 4 + i;
        size_t oidx = ((size_t)(h * 360) + n) * 361 + m;
        if (oidx < (size_t)out_elems) out[oidx] = av[i];
    }
}

// ---------------------------------------------------------------------------
// Fallback: fused, exact integer-phase double trig. Real-only or complex out.
// ---------------------------------------------------------------------------
__global__ __launch_bounds__(256) void fused_kernel(
    const float* __restrict__ x, const float* __restrict__ W,
    float* __restrict__ out, long long nx, long long nw, long long out_elems,
    int complexOut) {
    const int m   = blockIdx.x;
    const int tid = threadIdx.x;

    __shared__ float xl[16 * 360];

    for (int row = tid; row < NROWS; row += 256) {    // row = h*360 + k
        int h = row / 360, k = row % 360;
        const size_t base = (size_t)row * 720;
        float ar = 0.f, ai = 0.f;
        if (base + 720 <= (size_t)nx) {
            const float* xr = x + base;
            for (int j = 0; j < 720; ++j) {
                int p = (j * m) % 720;
                double a = ANGD * (double)p;
                float xe = xr[j];
                ar += xe * (float)(ANGD * cos(a));
                ai -= xe * (float)(ANGD * sin(a));
            }
        }
        xl[(h * 2) * 360 + k]     = ar;
        xl[(h * 2 + 1) * 360 + k] = ai;
    }
    __syncthreads();

    for (int n = tid; n < 360; n += 256) {
        float accr[8], acci[8];
#pragma unroll
        for (int i = 0; i < 8; ++i) { accr[i] = 0.f; acci[i] = 0.f; }
        const size_t wbase = ((size_t)m * 360 + n) * 360;
        if (wbase + 360 <= (size_t)nw) {
            const float* wr = W + wbase;
            for (int k = 0; k < 360; ++k) {
                float w = wr[k];
#pragma unroll
                for (int h = 0; h < 8; ++h) {
                    accr[h] += w * xl[(h * 2) * 360 + k];
                    acci[h] += w * xl[(h * 2 + 1) * 360 + k];
                }
            }
        }
#pragma unroll
        for (int h = 0; h < 8; ++h) {
            size_t e = ((size_t)(h * 360) + n) * 361 + m;
            if (complexOut) {
                if (2 * e + 1 < (size_t)out_elems) {
                    out[2 * e]     = accr[h];
                    out[2 * e + 1] = acci[h];
                }
            } else {
                if (e < (size_t)out_elems) out[e] = accr[h];
            }
        }
    }
}

extern "C" void kernel_launch(void* const* d_in, const int* in_sizes, int n_in,
                              void* d_out, int out_size, void* d_ws, size_t ws_size,
                              hipStream_t stream) {
    if (n_in < 2) return;
    const float* x = (const float*)d_in[0];   // [1,8,360,720] float32
    const float* W = (const float*)d_in[1];   // [361,360,360] float32
    float* out = (float*)d_out;               // float32[out_size]; expected = Re(result)

    const long long nx = in_sizes[0];
    const long long nw = in_sizes[1];
    const long long out_elems = (long long)out_size;
    const bool complexOut = (out_elems >= 2LL * 1039680LL);
    const bool sizesOk = (nx >= 2073600LL) && (nw >= 46785600LL);

    int S = 0;
    const size_t needT = TC_ELEMS * sizeof(float);
    for (int c = 4; c >= 1; c >>= 1) {
        if (ws_size >= needT + (size_t)c * P_STRIDE * sizeof(float)) { S = c; break; }
    }

    if (!complexOut && sizesOk && S > 0 && d_ws != nullptr) {
        float* Tc = (float*)d_ws;
        float* P  = Tc + TC_ELEMS;
        tw_init_kernel<<<(int)((TC_ELEMS + 255) / 256), 256, 0, stream>>>(Tc);
        dft_re_kernel<<<dim3(3, 45, S), 256, 0, stream>>>(x, Tc, P, S);
        contract_re_kernel<<<dim3(3, 361), 256, 0, stream>>>(W, P, out, S, out_elems);
    } else {
        fused_kernel<<<dim3(361), 256, 0, stream>>>(x, W, out, nx, nw, out_elems,
                                                    complexOut ? 1 : 0);
    }
}

// Round 8
// 344.885 us; speedup vs baseline: 1.0787x; 1.0787x over previous
//
#include <hip/hip_runtime.h>
#include <math.h>

// Problem constants
#define NTHETA  360
#define NLAMBDA 720
#define MMAX    361
#define NROWS   2880                       /* 8 heads * 360 theta rows */
#define ANGD (6.283185307179586476925286766559 / 720.0)  /* 2*pi/720 */

// DFT tiling
#define MT 128          /* m-tile per block (3 tiles cover 384 >= 361)   */
#define RT 64           /* row-tile per block (45 tiles cover 2880)      */
#define JC 36           /* j chunk staged in LDS (divides 720/S, mult 4) */
#define MPAD 384        /* padded m extent of cos table / partials       */

// Workspace: Tc[720][384] | P[S][384][2880] | outT[361][8][360]
#define TC_ELEMS   ((size_t)720 * MPAD)            /* 276,480 floats   */
#define P_STRIDE   ((size_t)MPAD * NROWS)          /* 1,105,920 floats */
#define OUTT_ELEMS ((size_t)MMAX * 8 * NTHETA)     /* 1,039,680 floats */

// ---------------------------------------------------------------------------
// Cos table: Tc[j*384+mp] = (2pi/720)*cos(2pi*(j*mp mod 720)/720), 0 for mp>=361.
// ---------------------------------------------------------------------------
__global__ __launch_bounds__(256) void tw_init_kernel(float* __restrict__ Tc) {
    int i = blockIdx.x * 256 + threadIdx.x;
    if (i >= (int)TC_ELEMS) return;
    int j = i / MPAD, mp = i % MPAD;
    float v = 0.f;
    if (mp < MMAX) {
        int p = (j * mp) % 720;                      // exact integer phase
        v = (float)ANGD * cosf((float)(ANGD * (double)p));
    }
    Tc[i] = v;
}

// ---------------------------------------------------------------------------
// Real DFT as register-tiled GEMM (x and Tc both LDS-staged):
//   P[s][mp][row] = sum_{j in split s} x[row][j] * Tc[j][mp]
// grid (3 mtile, 45 rtile, S), block 256 = (tm 16)x(tr 16); thread: 8m x 4r accs.
// ---------------------------------------------------------------------------
__global__ __launch_bounds__(256) void dft_re_kernel(
    const float* __restrict__ x, const float* __restrict__ Tc,
    float* __restrict__ P, int S) {
    const int mt  = blockIdx.x;
    const int rt  = blockIdx.y;
    const int s   = blockIdx.z;
    const int tid = threadIdx.x;
    const int tm  = tid & 15;
    const int tr  = tid >> 4;
    const int m0g = mt * MT;            // block m base (global)
    const int mo  = tm * 8;             // thread m offset in tile
    const int rb  = rt * RT;            // block row base
    const int tr4 = tr * 4;             // thread row offset
    const int jlen = 720 / S;
    const int j0   = s * jlen;

    __shared__ __align__(16) float tc[JC][MT + 4];   // 19 KB
    __shared__ float xs[JC][65];                     // 9.2 KB, [j][row] pitch 65

    float acc[8][4];
#pragma unroll
    for (int a = 0; a < 8; ++a)
#pragma unroll
        for (int b = 0; b < 4; ++b) acc[a][b] = 0.f;

    for (int jc = 0; jc < jlen; jc += JC) {
        __syncthreads();
        for (int i = tid; i < JC * MT; i += 256) {
            int jj = i >> 7;            // /128
            int mm = i & (MT - 1);
            tc[jj][mm] = Tc[(size_t)(j0 + jc + jj) * MPAD + m0g + mm];
        }
        for (int i = tid; i < JC * RT; i += 256) {
            int jj = i % JC;            // fast -> coalesced within x rows
            int rr = i / JC;
            xs[jj][rr] = x[(size_t)(rb + rr) * 720 + j0 + jc + jj];
        }
        __syncthreads();

        for (int jb = 0; jb < JC; jb += 4) {
#pragma unroll
            for (int u = 0; u < 4; ++u) {
                float4 ta = *(const float4*)&tc[jb + u][mo];
                float4 tb = *(const float4*)&tc[jb + u][mo + 4];
                float xr0 = xs[jb + u][tr4 + 0];
                float xr1 = xs[jb + u][tr4 + 1];
                float xr2 = xs[jb + u][tr4 + 2];
                float xr3 = xs[jb + u][tr4 + 3];
#pragma unroll
                for (int i = 0; i < 4; ++i) {
                    float xe = (i == 0) ? xr0 : (i == 1) ? xr1 : (i == 2) ? xr2 : xr3;
                    acc[0][i] += ta.x * xe;
                    acc[1][i] += ta.y * xe;
                    acc[2][i] += ta.z * xe;
                    acc[3][i] += ta.w * xe;
                    acc[4][i] += tb.x * xe;
                    acc[5][i] += tb.y * xe;
                    acc[6][i] += tb.z * xe;
                    acc[7][i] += tb.w * xe;
                }
            }
        }
    }

#pragma unroll
    for (int mi = 0; mi < 8; ++mi) {
        float* dst = P + ((size_t)s * MPAD + m0g + mo + mi) * NROWS + rb + tr4;
        *(float4*)dst = make_float4(acc[mi][0], acc[mi][1], acc[mi][2], acc[mi][3]);
    }
}

// ---------------------------------------------------------------------------
// Sum j-split partials into P[0]
// ---------------------------------------------------------------------------
__global__ __launch_bounds__(256) void reduce_kernel(float* __restrict__ P, int S) {
    size_t i = ((size_t)blockIdx.x * 256 + threadIdx.x) * 4;
    if (i >= P_STRIDE) return;
    float4 a = *(float4*)&P[i];
    for (int s = 1; s < S; ++s) {
        float4 b = *(const float4*)&P[(size_t)s * P_STRIDE + i];
        a.x += b.x; a.y += b.y; a.z += b.z; a.w += b.w;
    }
    *(float4*)&P[i] = a;
}

// ---------------------------------------------------------------------------
// Contraction (real part only), register-double-buffered W stream:
//   outT[m][h][n] = sum_k P0[m][h*360+k] * W[m][n][k]
// grid (6 nch, 361 m), block 128: n = nch*64 + tid/2, cg = tid&1 -> 4 heads.
// ---------------------------------------------------------------------------
__global__ __launch_bounds__(128) void contract_re_kernel(
    const float* __restrict__ W, const float* __restrict__ P0,
    float* __restrict__ outT) {
    const int nch = blockIdx.x;
    const int m   = blockIdx.y;
    const int tid = threadIdx.x;

    __shared__ __align__(16) float xl[NROWS];         // 11.5 KB
    for (int i = tid * 4; i < NROWS; i += 128 * 4)
        *(float4*)&xl[i] = *(const float4*)&P0[(size_t)m * NROWS + i];
    __syncthreads();

    const int n  = nch * 64 + (tid >> 1);
    const int cg = tid & 1;
    if (n >= NTHETA) return;

    const float4* wp = (const float4*)(W + ((size_t)m * 360 + n) * 360);  // 90 float4
    const float* xb = xl + cg * 4 * 360;

    float a0 = 0.f, a1 = 0.f, a2 = 0.f, a3 = 0.f;
    float4 wb[6], wn[6];
#pragma unroll
    for (int q = 0; q < 6; ++q) wb[q] = wp[q];

#pragma unroll
    for (int c = 0; c < 15; ++c) {
        const int cn = (c < 14) ? c + 1 : 14;
#pragma unroll
        for (int q = 0; q < 6; ++q) wn[q] = wp[cn * 6 + q];   // prefetch next chunk
#pragma unroll
        for (int q = 0; q < 6; ++q) {
            const int kk = c * 24 + q * 4;
            float4 v0 = *(const float4*)(xb + 0 * 360 + kk);
            float4 v1 = *(const float4*)(xb + 1 * 360 + kk);
            float4 v2 = *(const float4*)(xb + 2 * 360 + kk);
            float4 v3 = *(const float4*)(xb + 3 * 360 + kk);
            a0 += wb[q].x * v0.x + wb[q].y * v0.y + wb[q].z * v0.z + wb[q].w * v0.w;
            a1 += wb[q].x * v1.x + wb[q].y * v1.y + wb[q].z * v1.z + wb[q].w * v1.w;
            a2 += wb[q].x * v2.x + wb[q].y * v2.y + wb[q].z * v2.z + wb[q].w * v2.w;
            a3 += wb[q].x * v3.x + wb[q].y * v3.y + wb[q].z * v3.z + wb[q].w * v3.w;
        }
#pragma unroll
        for (int q = 0; q < 6; ++q) wb[q] = wn[q];
    }

    float av[4] = {a0, a1, a2, a3};
#pragma unroll
    for (int i = 0; i < 4; ++i) {
        int h = cg * 4 + i;
        outT[((size_t)m * 8 + h) * 360 + n] = av[i];   // coalesced along n
    }
}

// ---------------------------------------------------------------------------
// Transpose outT[m][h][n] -> out[h][n][m], LDS-tiled, coalesced both sides.
// grid (12 mt, 12 nt, 8 h), block (32, 8).
// ---------------------------------------------------------------------------
__global__ __launch_bounds__(256) void transpose_kernel(
    const float* __restrict__ outT, float* __restrict__ out, long long out_elems) {
    __shared__ float t[32][33];
    const int mt = blockIdx.x, nt = blockIdx.y, h = blockIdx.z;
    const int cx = threadIdx.x, cy = threadIdx.y;

#pragma unroll
    for (int ri = 0; ri < 4; ++ri) {
        int r = cy + ri * 8;                 // m offset in tile
        int mm = mt * 32 + r, nn = nt * 32 + cx;
        t[r][cx] = (mm < MMAX && nn < NTHETA)
                 ? outT[((size_t)mm * 8 + h) * 360 + nn] : 0.f;
    }
    __syncthreads();
#pragma unroll
    for (int ri = 0; ri < 4; ++ri) {
        int r = cy + ri * 8;                 // n offset in tile
        int nn = nt * 32 + r, mm = mt * 32 + cx;
        if (mm < MMAX && nn < NTHETA) {
            size_t oidx = ((size_t)(h * 360) + nn) * 361 + mm;
            if (oidx < (size_t)out_elems) out[oidx] = t[cx][r];
        }
    }
}

// ---------------------------------------------------------------------------
// Fallback: fused, exact integer-phase double trig. Real-only or complex out.
// ---------------------------------------------------------------------------
__global__ __launch_bounds__(256) void fused_kernel(
    const float* __restrict__ x, const float* __restrict__ W,
    float* __restrict__ out, long long nx, long long nw, long long out_elems,
    int complexOut) {
    const int m   = blockIdx.x;
    const int tid = threadIdx.x;

    __shared__ float xl[16 * 360];

    for (int row = tid; row < NROWS; row += 256) {    // row = h*360 + k
        int h = row / 360, k = row % 360;
        const size_t base = (size_t)row * 720;
        float ar = 0.f, ai = 0.f;
        if (base + 720 <= (size_t)nx) {
            const float* xr = x + base;
            for (int j = 0; j < 720; ++j) {
                int p = (j * m) % 720;
                double a = ANGD * (double)p;
                float xe = xr[j];
                ar += xe * (float)(ANGD * cos(a));
                ai -= xe * (float)(ANGD * sin(a));
            }
        }
        xl[(h * 2) * 360 + k]     = ar;
        xl[(h * 2 + 1) * 360 + k] = ai;
    }
    __syncthreads();

    for (int n = tid; n < 360; n += 256) {
        float accr[8], acci[8];
#pragma unroll
        for (int i = 0; i < 8; ++i) { accr[i] = 0.f; acci[i] = 0.f; }
        const size_t wbase = ((size_t)m * 360 + n) * 360;
        if (wbase + 360 <= (size_t)nw) {
            const float* wr = W + wbase;
            for (int k = 0; k < 360; ++k) {
                float w = wr[k];
#pragma unroll
                for (int h = 0; h < 8; ++h) {
                    accr[h] += w * xl[(h * 2) * 360 + k];
                    acci[h] += w * xl[(h * 2 + 1) * 360 + k];
                }
            }
        }
#pragma unroll
        for (int h = 0; h < 8; ++h) {
            size_t e = ((size_t)(h * 360) + n) * 361 + m;
            if (complexOut) {
                if (2 * e + 1 < (size_t)out_elems) {
                    out[2 * e]     = accr[h];
                    out[2 * e + 1] = acci[h];
                }
            } else {
                if (e < (size_t)out_elems) out[e] = accr[h];
            }
        }
    }
}

extern "C" void kernel_launch(void* const* d_in, const int* in_sizes, int n_in,
                              void* d_out, int out_size, void* d_ws, size_t ws_size,
                              hipStream_t stream) {
    if (n_in < 2) return;
    const float* x = (const float*)d_in[0];   // [1,8,360,720] float32
    const float* W = (const float*)d_in[1];   // [361,360,360] float32
    float* out = (float*)d_out;               // float32[out_size]; expected = Re(result)

    const long long nx = in_sizes[0];
    const long long nw = in_sizes[1];
    const long long out_elems = (long long)out_size;
    const bool complexOut = (out_elems >= 2LL * 1039680LL);
    const bool sizesOk = (nx >= 2073600LL) && (nw >= 46785600LL);

    int S = 0;
    for (int c = 4; c >= 1; c >>= 1) {
        size_t need = (TC_ELEMS + (size_t)c * P_STRIDE + OUTT_ELEMS) * sizeof(float);
        if (ws_size >= need) { S = c; break; }
    }

    if (!complexOut && sizesOk && S > 0 && d_ws != nullptr) {
        float* Tc = (float*)d_ws;
        float* P  = Tc + TC_ELEMS;
        float* oT = P + (size_t)S * P_STRIDE;
        tw_init_kernel<<<(int)((TC_ELEMS + 255) / 256), 256, 0, stream>>>(Tc);
        dft_re_kernel<<<dim3(3, 45, S), 256, 0, stream>>>(x, Tc, P, S);
        if (S > 1)
            reduce_kernel<<<(int)((P_STRIDE / 4 + 255) / 256), 256, 0, stream>>>(P, S);
        contract_re_kernel<<<dim3(6, 361), 128, 0, stream>>>(W, P, oT);
        transpose_kernel<<<dim3(12, 12, 8), dim3(32, 8), 0, stream>>>(oT, out, out_elems);
    } else {
        fused_kernel<<<dim3(361), 256, 0, stream>>>(x, W, out, nx, nw, out_elems,
                                                    complexOut ? 1 : 0);
    }
}